// Round 10
// baseline (1310.187 us; speedup 1.0000x reference)
//
#include <hip/hip_runtime.h>
#include <hip/hip_bf16.h>

// EarthAttention2D on MI355X (gfx950).
// B_WIN=2048, N=128, DIM=512, HEADS=16, hd=32, M = 2048*128 = 262144.
// Pipeline: cvt_x (x->bf16) + prep (weights->bf16, epb gather)
//        -> QKV GEMM (r2-proven loop: BK=64, single 32KiB buffer, GLDS both
//           operands, XOR-swizzled reads; single-pass epilogue ->
//           head-major Q/K/V[b,h,n,d])
//        -> fused window attention (40960B LDS = 4 blocks/CU, XOR-swizzled
//           Ps/Vt, no pads)
//        -> proj GEMM (same loop, f32 out).
//
// LESSONS ENCODED:
//  - r6: never pin __launch_bounds__ min-waves above the acc working set.
//  - r8: epilogue must be single unconditional pass (acc liveness).
//  - r9: VGPR granule -> blocks/CU is THE lever in this short-K regime.
//  - r10: attention is latency-bound (21k cyc/block vs ~3k compute);
//         LDS 43520->40960 buys the 4th block/CU. bk loaded in-loop to
//         keep VGPR <= 128 (4 waves/SIMD budget).
//
// GEMM LDS swizzle (BK=64, 128B rows): LDS[r][c16] = global[r][c16^(r&7)]
// (inverse swizzle on the GLDS *source*, linear dest - m173);
// ds_read addr (r*128+cb)^((lo&7)<<4) -> conflict-free.
// Attn Ps/Vt swizzle: byte addr ^= ((row&7)<<4) on [row][128col] u16 rows;
// b128 row-reads spread quarter-wave over 8 bank-groups (2-way = free).

typedef short short8 __attribute__((ext_vector_type(8)));
typedef float f32x4 __attribute__((ext_vector_type(4)));
typedef unsigned short u16;
typedef unsigned int u32;

__device__ __forceinline__ u16 f2bf(float f) {
    __bf16 h = (__bf16)f;                    // RNE fptrunc -> v_cvt on gfx950
    union { __bf16 b; u16 u; } v; v.b = h;
    return v.u;
}

__device__ __forceinline__ f32x4 mfma16(short8 a, short8 b, f32x4 c) {
    return __builtin_amdgcn_mfma_f32_16x16x32_bf16(a, b, c, 0, 0, 0);
}

// async global->LDS, 16B per lane, dest = wave-uniform base + lane*16
#define GLDS16(gsrc, ldst)                                                  \
    __builtin_amdgcn_global_load_lds(                                       \
        (const __attribute__((address_space(1))) void*)(gsrc),              \
        (__attribute__((address_space(3))) void*)(ldst), 16, 0, 0)

// ---------------------------------------------------------------- cvt_x ----
__global__ __launch_bounds__(256) void cvt_x_kernel(
    const float4* __restrict__ xin, int4* __restrict__ xbf)
{
    int idx = blockIdx.x * 256 + threadIdx.x;           // unit = 8 floats
    for (; idx < 16777216; idx += 8192 * 256) {
        const float4 a = xin[idx * 2], b = xin[idx * 2 + 1];
        int4 o;
        o.x = (u32)f2bf(a.x) | ((u32)f2bf(a.y) << 16);
        o.y = (u32)f2bf(a.z) | ((u32)f2bf(a.w) << 16);
        o.z = (u32)f2bf(b.x) | ((u32)f2bf(b.y) << 16);
        o.w = (u32)f2bf(b.z) | ((u32)f2bf(b.w) << 16);
        xbf[idx] = o;
    }
}

// ---------------------------------------------------------------- prep ----
__global__ __launch_bounds__(256) void prep_kernel(
    const float* __restrict__ qkv_w, const float* __restrict__ proj_w,
    const float* __restrict__ btab, const int* __restrict__ pidx,
    u16* __restrict__ qkvw_bf, u16* __restrict__ projw_bf,
    float* __restrict__ epb)
{
    const int i = blockIdx.x * 256 + threadIdx.x;    // grid = 3072*256 = 786432
    qkvw_bf[i] = f2bf(qkv_w[i]);
    if (i < 512 * 512) projw_bf[i] = f2bf(proj_w[i]);
    if (i < 16 * 128 * 128) {
        const int rc = i & 16383, h = i >> 14;
        epb[i] = btab[pidx[rc] * 128 + 64 + h];      // bias_table[idx][TOW/2=4][h]
    }
}

// ---------------------------------------------------------------- GEMM ----
// C[M,Nn] = A[M,K] @ Bt[Nn,K]^T (+bias).  128x128 tile, BK=64, 4 waves.
// LDS: single buffer A[128][64] + B[128][64] = 32 KiB -> 5 blocks/CU.
// Loop (r2-proven): STAGE(0); { sync(drain); ds_read+32 MFMA; sync; STAGE }.
//
// EPI_QKV: tsel = bn>>2 (0=Q,1=K,2=V), 4 heads per tile; single-pass
// [128][128] LDS restage then coalesced int4 scatter to
// out[((b*16+h)*128 + n)*32 + d], scale=qscale iff tsel==0.
// else: f32 direct stores (+bias) to Cv.

template<bool EPI_QKV>
__global__ __launch_bounds__(256) void gemm_bt(
    const u16* __restrict__ A, const u16* __restrict__ Bt,
    const float* __restrict__ bias, void* __restrict__ Cv,
    u16* __restrict__ kb, u16* __restrict__ vb,
    const int Nn, const int K, const float qscale)
{
    __shared__ __attribute__((aligned(16))) char sm[32768];
    char* As = sm;                  // [128] rows x 128B, swizzled content
    char* Bs = sm + 16384;

    const int tid = threadIdx.x;
    const int lane = tid & 63;
    const int w = tid >> 6;
    const int lo = lane & 15, g = lane >> 4;
    const int wm = w >> 1, wn = w & 1;
    const int wofs = __builtin_amdgcn_readfirstlane(w) * 1024;
    const int ntile = Nn >> 7;

    int wg = blockIdx.x;
    {   // bijective XCD swizzle (gridDim % 8 == 0 for all launches)
        const int cpx = gridDim.x >> 3;
        wg = (wg & 7) * cpx + (wg >> 3);
    }
    const int bm = wg / ntile, bn = wg % ntile;
    const size_t m0 = (size_t)bm << 7;
    const int n0 = bn << 7;
    const int nk = K >> 6;                               // 8

    // per-lane global source pointers: slot s = i*256+tid; r=s>>3, c16=s&7;
    // source col-chunk = c16 ^ (r&7)  (inverse swizzle, m173 pattern)
    const u16* pa[4];
    const u16* pb[4];
#pragma unroll
    for (int i = 0; i < 4; ++i) {
        const int s = i * 256 + tid;
        const int r = s >> 3, c16 = s & 7;
        const int csw = (c16 ^ (r & 7)) << 3;            // element offset
        pa[i] = A + (m0 + r) * (size_t)K + csw;
        pb[i] = Bt + (size_t)(n0 + r) * K + csw;
    }

#define STAGE(kt)                                                          \
    do {                                                                   \
        const int koff = (kt) * 64;                                        \
        _Pragma("unroll")                                                  \
        for (int i = 0; i < 4; ++i)                                        \
            GLDS16(pa[i] + koff, As + i * 4096 + wofs);                    \
        _Pragma("unroll")                                                  \
        for (int i = 0; i < 4; ++i)                                        \
            GLDS16(pb[i] + koff, Bs + i * 4096 + wofs);                    \
    } while (0)

    f32x4 acc[4][4] = {};

    STAGE(0);
    for (int kt = 0;;) {
        __syncthreads();            // drains vmcnt -> tile kt resident
#pragma unroll
        for (int kk = 0; kk < 2; ++kk) {
            short8 af[4], bq[4];
            const int cb = (kk * 4 + g) << 4;            // byte col-chunk
            const int sz = (lo & 7) << 4;                // row XOR swizzle
#pragma unroll
            for (int i = 0; i < 4; ++i) {
                const int ra = wm * 64 + i * 16 + lo;
                af[i] = *(const short8*)(As + ((ra * 128 + cb) ^ sz));
                const int rb = wn * 64 + i * 16 + lo;
                bq[i] = *(const short8*)(Bs + ((rb * 128 + cb) ^ sz));
            }
#pragma unroll
            for (int i = 0; i < 4; ++i)
#pragma unroll
                for (int j = 0; j < 4; ++j)
                    acc[i][j] = mfma16(af[i], bq[j], acc[i][j]);
        }
        if (++kt == nk) break;
        __syncthreads();            // all reads done; LDS free for next tile
        STAGE(kt);
    }
#undef STAGE

    if constexpr (EPI_QKV) {
        // single-pass epilogue: restage [128][128] bf16 (32 KiB),
        // then coalesced int4 scatter to head-major [b,h,n,32].
        __syncthreads();
        u16* Ct = (u16*)sm;
        const int b16 = ((int)(m0 >> 7)) * 16;
        const int tsel = bn >> 2;                        // 0=q,1=k,2=v (uniform)
        const int h0 = (bn & 3) << 2;
        u16* outb = (tsel == 0) ? (u16*)Cv : (tsel == 1) ? kb : vb;
        const float sc = (tsel == 0) ? qscale : 1.0f;
#pragma unroll
        for (int j = 0; j < 4; ++j) {
            const int c = wn * 64 + j * 16 + lo;
            const float bv = bias[n0 + c];
#pragma unroll
            for (int i = 0; i < 4; ++i)
#pragma unroll
                for (int ii = 0; ii < 4; ++ii) {
                    const int r = wm * 64 + i * 16 + g * 4 + ii;
                    Ct[r * 128 + c] = f2bf((acc[i][j][ii] + bv) * sc);
                }
        }
        __syncthreads();
#pragma unroll
        for (int it = 0; it < 8; ++it) {
            const int idx = it * 256 + tid;
            const int r = idx >> 4, s2 = idx & 15;
            const int hl = s2 >> 2, d0 = (s2 & 3) * 8;
            *(int4*)(outb + ((size_t)(b16 + h0 + hl) * 128 + r) * 32 + d0) =
                *(const int4*)(Ct + r * 128 + s2 * 8);
        }
    } else {
        float* Cg = (float*)Cv;
#pragma unroll
        for (int j = 0; j < 4; ++j) {
            const int c = wn * 64 + j * 16 + lo;
            const float bv = bias[n0 + c];
#pragma unroll
            for (int i = 0; i < 4; ++i)
#pragma unroll
                for (int ii = 0; ii < 4; ++ii) {
                    const size_t r = m0 + wm * 64 + i * 16 + g * 4 + ii;
                    Cg[r * (size_t)Nn + n0 + c] = acc[i][j][ii] + bv;
                }
        }
    }
}

// ----------------------------------------------------------- attention ----
// One block (4 waves) per (b, h).  Inputs head-major: Q/K/V[b,h,n,d].
// LDS = 40960 B -> 4 blocks/CU (was 43520 -> 3):
//   [0, 8192):     Vt [32 d][128 c] u16, XOR-swz; phase3: Os [128][32]
//   [8192, 40960): phase1: Qs [+0, 8K), Ks [+8K, 16K)  (quarter-wave swz)
//                  phase2: Ps, wave w at +w*8192, [32 r][128 c] XOR-swz
// bk fragments loaded inside the QK^T loop (not prefetched) to keep
// VGPR <= 128 = the 4-waves/SIMD budget.
__global__ __launch_bounds__(256) void attn_kernel(
    const u16* __restrict__ qbuf, const u16* __restrict__ kbuf,
    const u16* __restrict__ vbuf, const float* __restrict__ epb,
    u16* __restrict__ aout)
{
    __shared__ __attribute__((aligned(16))) char smem[40960];
    char* Vts = smem;                                    // [32][128] swz
    char* Qs  = smem + 8192;                             // [128][32] swz
    char* Ks  = smem + 16384;                            // [128][32] swz
    u16 (*Os)[32] = (u16(*)[32])smem;                    // phase3

    const int h = blockIdx.x >> 11;
    const int b = blockIdx.x & 2047;
    const int tid = threadIdx.x;
    const int lane = tid & 63, w = tid >> 6;
    const int lo = lane & 15, g = lane >> 4;
    const int wu = __builtin_amdgcn_readfirstlane(w);

    const size_t hb = (size_t)(b * 16 + h) * 4096;
    const u16* qp = qbuf + hb;
    const u16* kp = kbuf + hb;
    const u16* vp = vbuf + hb;

    // Q/K via global_load_lds with inverse-swizzled source (64B rows)
    const int c8 = ((lane & 3) ^ ((lane >> 3) & 3)) * 8;
    const int rofs = (lane >> 2) * 32;
#pragma unroll
    for (int cc = 0; cc < 2; ++cc) {
        const int ch = wu * 2 + cc;
        GLDS16(qp + ch * 512 + rofs + c8, Qs + ch * 1024);
        GLDS16(kp + ch * 512 + rofs + c8, Ks + ch * 1024);
    }
    // V: coalesced int4 loads, transpose via scalar writes into swz [32][128]
#pragma unroll
    for (int it = 0; it < 2; ++it) {
        const int idx = tid + it * 256;          // 0..511
        const int n = idx >> 2, d8 = (idx & 3) * 8;
        union { int4 q; u16 u[8]; } vu;
        vu.q = *(const int4*)(vp + n * 32 + d8);
#pragma unroll
        for (int j = 0; j < 8; ++j) {
            const int d = d8 + j;
            *(u16*)(Vts + ((d * 256 + n * 2) ^ ((d & 7) << 4))) = vu.u[j];
        }
    }
    __syncthreads();

    const int r0 = w * 32;
    const int csw16 = (g ^ ((lo >> 1) & 3)) << 4;   // Q/K ds_read col swizzle

    // ---- S = Q @ K^T ----  (bk in-loop: liveness 1, not 32 VGPRs)
    const short8 aq0 = *(const short8*)(Qs + (r0 + lo) * 64 + csw16);
    const short8 aq1 = *(const short8*)(Qs + (r0 + 16 + lo) * 64 + csw16);
    f32x4 acc[2][8];
#pragma unroll
    for (int j = 0; j < 8; ++j) {
        const short8 bk = *(const short8*)(Ks + (j * 16 + lo) * 64 + csw16);
        f32x4 z = {0.f, 0.f, 0.f, 0.f};
        acc[0][j] = mfma16(aq0, bk, z);
        acc[1][j] = mfma16(aq1, bk, z);
    }

    // ---- bias + row max ----
    const float* eb = epb + (h << 14);
    float mrow[2][4], rsum[2][4];
#pragma unroll
    for (int mt = 0; mt < 2; ++mt)
#pragma unroll
        for (int ii = 0; ii < 4; ++ii) { mrow[mt][ii] = -1e30f; rsum[mt][ii] = 0.f; }

#pragma unroll
    for (int mt = 0; mt < 2; ++mt)
#pragma unroll
        for (int j = 0; j < 8; ++j)
#pragma unroll
            for (int ii = 0; ii < 4; ++ii) {
                const int r = r0 + mt * 16 + g * 4 + ii;
                const int c = j * 16 + lo;
                const float sv = acc[mt][j][ii] + eb[(r << 7) + c];
                acc[mt][j][ii] = sv;
                mrow[mt][ii] = fmaxf(mrow[mt][ii], sv);
            }
#pragma unroll
    for (int d = 1; d < 16; d <<= 1)
#pragma unroll
        for (int mt = 0; mt < 2; ++mt)
#pragma unroll
            for (int ii = 0; ii < 4; ++ii)
                mrow[mt][ii] = fmaxf(mrow[mt][ii], __shfl_xor(mrow[mt][ii], d, 64));

    __syncthreads();   // all waves done reading Qs/Ks -> Ps may overwrite

    // ---- exp -> Ps (per-wave private swz region), row sums ----
    char* Pw = smem + 8192 + w * 8192;
#pragma unroll
    for (int mt = 0; mt < 2; ++mt)
#pragma unroll
        for (int j = 0; j < 8; ++j)
#pragma unroll
            for (int ii = 0; ii < 4; ++ii) {
                const float p = __expf(acc[mt][j][ii] - mrow[mt][ii]);
                rsum[mt][ii] += p;
                const int r = mt * 16 + g * 4 + ii;
                const int c = j * 16 + lo;
                *(u16*)(Pw + ((r * 256 + c * 2) ^ ((r & 7) << 4))) = f2bf(p);
            }
#pragma unroll
    for (int d = 1; d < 16; d <<= 1)
#pragma unroll
        for (int mt = 0; mt < 2; ++mt)
#pragma unroll
            for (int ii = 0; ii < 4; ++ii)
                rsum[mt][ii] += __shfl_xor(rsum[mt][ii], d, 64);

    // ---- O = P @ V ----  (own-wave Ps: no barrier needed)
    const int psz = (lo & 7) << 4;
    f32x4 o[2][2] = {};
#pragma unroll
    for (int kk = 0; kk < 4; ++kk) {
        const int cb = (kk * 32 + g * 8) * 2;
        const short8 av0 = *(const short8*)(Pw + ((lo * 256 + cb) ^ psz));
        const short8 av1 = *(const short8*)(Pw + (((16 + lo) * 256 + cb) ^ psz));
#pragma unroll
        for (int dt = 0; dt < 2; ++dt) {
            const short8 bv =
                *(const short8*)(Vts + (((dt * 16 + lo) * 256 + cb) ^ psz));
            o[0][dt] = mfma16(av0, bv, o[0][dt]);
            o[1][dt] = mfma16(av1, bv, o[1][dt]);
        }
    }

    __syncthreads();   // all waves done with Vt/Ps -> Os may overwrite

    // ---- normalize -> Os, coalesced int4 stores ----
#pragma unroll
    for (int mt = 0; mt < 2; ++mt)
#pragma unroll
        for (int dt = 0; dt < 2; ++dt)
#pragma unroll
            for (int ii = 0; ii < 4; ++ii)
                Os[r0 + mt * 16 + g * 4 + ii][dt * 16 + lo] =
                    f2bf(o[mt][dt][ii] / rsum[mt][ii]);
    __syncthreads();

    u16* op = aout + (size_t)b * 128 * 512 + h * 32;
#pragma unroll
    for (int it = 0; it < 2; ++it) {
        const int idx = tid + it * 256;          // 0..511
        const int r = idx >> 2, c = (idx & 3) * 8;
        *(int4*)(op + (size_t)r * 512 + c) = *(const int4*)(&Os[r][c]);
    }
}

// -------------------------------------------------------------- launch ----
extern "C" void kernel_launch(void* const* d_in, const int* in_sizes, int n_in,
                              void* d_out, int out_size, void* d_ws, size_t ws_size,
                              hipStream_t stream)
{
    const float* x      = (const float*)d_in[0];
    const float* qkv_w  = (const float*)d_in[1];
    const float* qkv_b  = (const float*)d_in[2];
    const float* proj_w = (const float*)d_in[3];
    const float* proj_b = (const float*)d_in[4];
    const float* btab   = (const float*)d_in[5];
    const int*   pidx   = (const int*)d_in[6];

    // workspace layout (bytes), total 1,076,887,552
    // xbf aliases attnbuf: x_bf16 is dead before attn writes its output.
    char* ws = (char*)d_ws;
    u16*   xbf      = (u16*)(ws);                        // 268,435,456
    u16*   attnbuf  = (u16*)(ws);                        // (alias)
    u16*   qkvw_bf  = (u16*)(ws + 268435456);            //   1,572,864
    u16*   projw_bf = (u16*)(ws + 270008320);            //     524,288
    float* epb      = (float*)(ws + 270532608);          //   1,048,576
    u16*   qbuf     = (u16*)(ws + 271581184);            // 268,435,456
    u16*   kbuf     = (u16*)(ws + 540016640);            // 268,435,456
    u16*   vbuf     = (u16*)(ws + 808452096);            // 268,435,456

    const float qscale = 0.17677669529663687f;           // 32^-0.5

    cvt_x_kernel<<<dim3(8192), dim3(256), 0, stream>>>(
        (const float4*)x, (int4*)xbf);

    prep_kernel<<<dim3(3072), dim3(256), 0, stream>>>(
        qkv_w, proj_w, btab, pidx, qkvw_bf, projw_bf, epb);

    // QKV: [262144,512]bf16 @ [1536,512]bf16^T -> Q/K/V head-major buffers
    gemm_bt<true><<<dim3(2048 * 12), dim3(256), 0, stream>>>(
        xbf, qkvw_bf, qkv_b, qbuf, kbuf, vbuf, 1536, 512, qscale);

    // fused window attention: 2048 windows x 16 heads
    attn_kernel<<<dim3(32768), dim3(256), 0, stream>>>(
        qbuf, kbuf, vbuf, epb, attnbuf);

    // proj: [262144,512]bf16 @ [512,512]bf16^T -> f32 (+bias)
    gemm_bt<false><<<dim3(2048 * 4), dim3(256), 0, stream>>>(
        attnbuf, projw_bf, proj_b, d_out, nullptr, nullptr, 512, 512, 1.0f);
}